// Round 1
// baseline (1293.097 us; speedup 1.0000x reference)
//
#include <hip/hip_runtime.h>

#define Bsz 4
#define Cin 64
#define C2c 128
#define Hh 256
#define Ww 256
#define Tt 16
#define HW (Hh*Ww)
#define ICC 8

// ---------- Wt[t*4+o][c] = W_out[o][c] * masks[t][c] ----------
__global__ void wt_kernel(const float* __restrict__ W_out,
                          const float* __restrict__ masks,
                          float* __restrict__ Wt) {
  int i = blockIdx.x * 256 + threadIdx.x;           // 8192 total
  if (i < Tt * 4 * C2c) {
    int to = i >> 7, c = i & 127;
    int t = to >> 2, o = to & 3;
    Wt[i] = W_out[o * C2c + c] * masks[t * C2c + c];
  }
}

// ---------- conv1: x[b,64,H,W] -> h[bi,128,H,W] ----------
// grid (W/32, H/32, nb*8 oc-chunks), block 256 (32x8), 4 rows/thread, 16 oc/block
__global__ __launch_bounds__(256) void conv1_kernel(
    const float* __restrict__ x, const float* __restrict__ Wc,
    const float* __restrict__ bc, float* __restrict__ h, int b0) {
  __shared__ float xt[ICC][34 * 34];
  const int tid = threadIdx.x;
  const int tx = tid & 31, ty = tid >> 5;
  const int x0 = blockIdx.x * 32, y0 = blockIdx.y * 32;
  const int oc0 = (blockIdx.z & 7) * 16;
  const int bi = blockIdx.z >> 3;
  const float* xb = x + (size_t)(b0 + bi) * Cin * HW;

  float acc[16][4];
  #pragma unroll
  for (int o = 0; o < 16; ++o)
    #pragma unroll
    for (int r = 0; r < 4; ++r) acc[o][r] = 0.f;

  #pragma unroll 1
  for (int icc = 0; icc < Cin; icc += ICC) {
    __syncthreads();
    for (int i = tid; i < ICC * 34 * 34; i += 256) {
      int icl = i / (34 * 34); int rem = i % (34 * 34);
      int yy = rem / 34, xx = rem % 34;
      int gy = y0 - 1 + yy, gx = x0 - 1 + xx;
      float v = 0.f;
      if ((unsigned)gy < Hh && (unsigned)gx < Ww)
        v = xb[(size_t)(icc + icl) * HW + gy * Ww + gx];
      xt[icl][rem] = v;
    }
    __syncthreads();
    #pragma unroll 2
    for (int icl = 0; icl < ICC; ++icl) {
      float xv[6][3];
      #pragma unroll
      for (int rr = 0; rr < 6; ++rr)
        #pragma unroll
        for (int cc = 0; cc < 3; ++cc)
          xv[rr][cc] = xt[icl][(ty * 4 + rr) * 34 + tx + cc];
      const float* wp = Wc + ((size_t)oc0 * Cin + (icc + icl)) * 9;
      #pragma unroll
      for (int o = 0; o < 16; ++o) {
        float w[9];
        #pragma unroll
        for (int k = 0; k < 9; ++k) w[k] = wp[(size_t)o * Cin * 9 + k];  // block-uniform -> s_load
        #pragma unroll
        for (int r = 0; r < 4; ++r) {
          float s = acc[o][r];
          #pragma unroll
          for (int k = 0; k < 9; ++k)
            s = fmaf(w[k], xv[r + k / 3][k % 3], s);
          acc[o][r] = s;
        }
      }
    }
  }
  float* hb = h + (size_t)bi * C2c * HW;
  #pragma unroll
  for (int o = 0; o < 16; ++o) {
    float bias = bc[oc0 + o];
    #pragma unroll
    for (int r = 0; r < 4; ++r)
      hb[(size_t)(oc0 + o) * HW + (size_t)(y0 + ty * 4 + r) * Ww + x0 + tx] = acc[o][r] + bias;
  }
}

// ---------- stage2: samples GEMV + stats + AU conv, fused ----------
// grid (W/32, H/8, nb), block 256 (32x8), 1 pixel/thread
__global__ __launch_bounds__(256) void stage2_kernel(
    const float* __restrict__ h, const float* __restrict__ Wt,
    const float* __restrict__ b_out, const float* __restrict__ W_aue,
    const float* __restrict__ b_aue, const float* __restrict__ lms,
    float* __restrict__ out, int b0) {
  __shared__ float ht[ICC][10 * 34];
  const int tid = threadIdx.x;
  const int tx = tid & 31, ty = tid >> 5;
  const int x0 = blockIdx.x * 32, y0 = blockIdx.y * 8;
  const int bi = blockIdx.z;
  const int b = b0 + bi;
  const float* hb = h + (size_t)bi * C2c * HW;
  const int px = x0 + tx, py = y0 + ty;

  float accs[64];
  #pragma unroll
  for (int i = 0; i < 64; ++i) accs[i] = 0.f;
  float accA[4] = {0.f, 0.f, 0.f, 0.f};

  #pragma unroll 1
  for (int icc = 0; icc < C2c; icc += ICC) {
    __syncthreads();
    for (int i = tid; i < ICC * 10 * 34; i += 256) {
      int icl = i / 340; int rem = i % 340;
      int yy = rem / 34, xx = rem % 34;
      int gy = y0 - 1 + yy, gx = x0 - 1 + xx;
      float v = 0.f;
      if ((unsigned)gy < Hh && (unsigned)gx < Ww)
        v = hb[(size_t)(icc + icl) * HW + gy * Ww + gx];
      ht[icl][rem] = v;
    }
    __syncthreads();
    float xh[ICC];
    #pragma unroll
    for (int icl = 0; icl < ICC; ++icl)
      xh[icl] = ht[icl][(ty + 1) * 34 + tx + 1];
    // 64 (t,o) dot-product accumulations; Wt loads are wave-uniform
    #pragma unroll
    for (int to = 0; to < 64; ++to) {
      const float4 w0 = *(const float4*)(Wt + (size_t)to * C2c + icc);
      const float4 w1 = *(const float4*)(Wt + (size_t)to * C2c + icc + 4);
      float s = accs[to];
      s = fmaf(w0.x, xh[0], s); s = fmaf(w0.y, xh[1], s);
      s = fmaf(w0.z, xh[2], s); s = fmaf(w0.w, xh[3], s);
      s = fmaf(w1.x, xh[4], s); s = fmaf(w1.y, xh[5], s);
      s = fmaf(w1.z, xh[6], s); s = fmaf(w1.w, xh[7], s);
      accs[to] = s;
    }
    // AU 3x3 conv from the same LDS tile
    #pragma unroll
    for (int icl = 0; icl < ICC; ++icl) {
      float n[9];
      #pragma unroll
      for (int k = 0; k < 9; ++k)
        n[k] = ht[icl][(ty + k / 3) * 34 + tx + k % 3];
      const float* wa = W_aue + (size_t)(icc + icl) * 9;
      #pragma unroll
      for (int o = 0; o < 4; ++o) {
        float s = accA[o];
        #pragma unroll
        for (int k = 0; k < 9; ++k)
          s = fmaf(wa[(size_t)o * C2c * 9 + k], n[k], s);  // uniform -> s_load
        accA[o] = s;
      }
    }
  }

  const size_t pixoff = (size_t)py * Ww + px;
  const size_t plane = (size_t)Bsz * 4 * HW;
  #pragma unroll
  for (int o = 0; o < 4; ++o) {
    float bo = b_out[o];
    float sv[Tt];
    float sum = 0.f;
    #pragma unroll
    for (int t = 0; t < Tt; ++t) {
      float v = accs[t * 4 + o] + bo;
      float e = __expf(2.f * v);
      float th = 1.f - 2.f / (e + 1.f);       // tanh(v), exact identity
      sv[t] = th; sum += th;
    }
    float m = sum * (1.f / 16.f);
    float var = 0.f;
    #pragma unroll
    for (int t = 0; t < Tt; ++t) { float d = sv[t] - m; var = fmaf(d, d, var); }
    var *= (1.f / 15.f);                       // ddof=1; lms const over t -> no effect on var
    float lm = lms[((size_t)b * 4 + o) * HW + pixoff];
    float au = accA[o] + b_aue[o];
    au = 1.f / (1.f + __expf(-au));
    size_t oidx = ((size_t)b * 4 + o) * HW + pixoff;
    out[oidx] = au;                 // AU
    out[plane + oidx] = var;        // EU
    out[2 * plane + oidx] = m + lm; // mean
  }
}

extern "C" void kernel_launch(void* const* d_in, const int* in_sizes, int n_in,
                              void* d_out, int out_size, void* d_ws, size_t ws_size,
                              hipStream_t stream) {
  const float* x      = (const float*)d_in[0];
  const float* lms    = (const float*)d_in[1];
  const float* W_conv = (const float*)d_in[2];
  const float* b_conv = (const float*)d_in[3];
  const float* W_out  = (const float*)d_in[4];
  const float* b_out  = (const float*)d_in[5];
  const float* W_aue  = (const float*)d_in[6];
  const float* b_aue  = (const float*)d_in[7];
  const float* masks  = (const float*)d_in[8];
  float* out = (float*)d_out;

  float* Wt = (float*)d_ws;                       // 8192 floats
  float* h  = (float*)d_ws + Tt * 4 * C2c;        // h buffer after Wt
  size_t need_full = (size_t)(Tt * 4 * C2c) * 4 + (size_t)Bsz * C2c * HW * 4;

  wt_kernel<<<dim3(32), dim3(256), 0, stream>>>(W_out, masks, Wt);

  if (ws_size >= need_full) {
    // all 4 batches in one pair of launches (h = 128 MiB in ws)
    conv1_kernel<<<dim3(8, 8, 32), dim3(256), 0, stream>>>(x, W_conv, b_conv, h, 0);
    stage2_kernel<<<dim3(8, 32, 4), dim3(256), 0, stream>>>(h, Wt, b_out, W_aue, b_aue, lms, out, 0);
  } else {
    // per-batch h reuse (needs 33.6 MB of ws); stream order serializes correctly
    for (int b = 0; b < Bsz; ++b) {
      conv1_kernel<<<dim3(8, 8, 8), dim3(256), 0, stream>>>(x, W_conv, b_conv, h, b);
      stage2_kernel<<<dim3(8, 32, 1), dim3(256), 0, stream>>>(h, Wt, b_out, W_aue, b_aue, lms, out, b);
    }
  }
}